// Round 4
// baseline (1282.970 us; speedup 1.0000x reference)
//
#include <hip/hip_runtime.h>
#include <cstdint>

// Problem constants (fixed by setup_inputs in the reference)
constexpr int Bb = 2048;
constexpr int Tt = 1024;
constexpr int Nn = 27;
constexpr int KH = 16;   // k-half per lane (2 halves cover padded k=0..31)

__device__ __forceinline__ float rcpf(float a) { return __builtin_amdgcn_rcpf(a); }
__device__ __forceinline__ float exp2f_fast(float a) { return __builtin_amdgcn_exp2f(a); }

#define LOG2E 1.4426950408889634f

// Fused LSTM + output projection, fp32 (no fp32 MFMA on CDNA4 -> pure VALU).
//
// v4: v3's split-K layout with the register-pressure spike removed.
// v3 post-mortem: VGPR_Count=96 < 144 weight floats => weights were spilled
// to AGPRs (one v_accvgpr move per FMA, ~200 extra VALU inst/step/wave,
// measured 385 vs ~180 source-level). Cause: #pragma unroll 2 doubled live
// transients, pushing PEAK pressure over the 256-reg budget of
// __launch_bounds__(64,2) (512-reg pool / 2 waves). Fix: unroll 1 + 32-bit
// loop indexing. Peak pressure est. ~186 -> weights stay in arch VGPRs.
//
// Layout: 2048 single-wave blocks, one batch row per wave (2 waves/SIMD).
// lane = half*32 + j: j = hidden unit (j<27 active), half = 16-wide k-chunk.
// Weights per lane: 4x16 (W_ih) + 4x16 (W_hh) + 16 (W_out) = 144 VGPRs.
// Partial z per half, combined with __shfl_xor(.,32).
// zx (x-contribution) for step t+1 is computed during step t's gate tail.
// W_ih/W_hh/gate-biases are pre-scaled by log2(e) so gates use native exp2.
__global__ __launch_bounds__(64, 2) void lstm_fused_kernel(
    const float* __restrict__ x,      // [B,T,N]
    const float* __restrict__ h0,     // [B,N]
    const float* __restrict__ c0,     // [B,N]
    const float* __restrict__ W_ih,   // [4N,N] gate order i,f,g,o
    const float* __restrict__ W_hh,   // [4N,N]
    const float* __restrict__ b_ih,   // [4N]
    const float* __restrict__ b_hh,   // [4N]
    const float* __restrict__ W_out,  // [N,N]
    const float* __restrict__ b_out,  // [N]
    float* __restrict__ out,          // [B,T,N]
    float* __restrict__ hn,           // [B,N]
    float* __restrict__ cn)           // [B,N]
{
    const int lane = threadIdx.x;         // 0..63
    const int j    = lane & 31;           // hidden unit
    const int half = lane >> 5;           // k-chunk index
    const int k0   = half * KH;           // first k of this lane's chunk
    const bool act = (j < Nn);
    const bool pub = (lane < Nn);         // half-0 active lanes: publish + store
    const int jj   = act ? j : (Nn - 1);  // clamped for safe weight loads
    const int bg   = blockIdx.x;          // batch row

    // one row per block; 32-wide (27 used + zeroed pad). double-buffered.
    __shared__ __align__(16) float xbuf[2][32];
    __shared__ __align__(16) float hbuf[2][32];

    // ---- weight chunks into registers (zero-padded for k>=27) ----
    // wih/whh pre-scaled by log2e (their only consumers are exp2-based gates)
    float wih[4][KH], whh[4][KH], wout[KH];
#pragma unroll
    for (int g = 0; g < 4; ++g) {
#pragma unroll
        for (int kk = 0; kk < KH; ++kk) {
            const int k = k0 + kk;
            wih[g][kk] = (k < Nn) ? W_ih[(g * Nn + jj) * Nn + k] * LOG2E : 0.0f;
            whh[g][kk] = (k < Nn) ? W_hh[(g * Nn + jj) * Nn + k] * LOG2E : 0.0f;
        }
    }
#pragma unroll
    for (int kk = 0; kk < KH; ++kk) {
        const int k = k0 + kk;
        wout[kk] = (k < Nn) ? W_out[jj * Nn + k] : 0.0f;
    }

    // biases live only in half 0 (the cross-half reduction adds them once)
    const float bz0 = (half == 0) ? (b_ih[0 * Nn + jj] + b_hh[0 * Nn + jj]) * LOG2E : 0.0f;
    const float bz1 = (half == 0) ? (b_ih[1 * Nn + jj] + b_hh[1 * Nn + jj]) * LOG2E : 0.0f;
    const float bz2 = (half == 0) ? (b_ih[2 * Nn + jj] + b_hh[2 * Nn + jj]) * LOG2E : 0.0f;
    const float bz3 = (half == 0) ? (b_ih[3 * Nn + jj] + b_hh[3 * Nn + jj]) * LOG2E : 0.0f;
    const float bo  = (half == 0) ? b_out[jj] : 0.0f;

    float c  = c0[bg * Nn + jj];   // cell state (duplicated across halves)
    float hv = h0[bg * Nn + jj];   // hidden state (duplicated)

    const float* xrow = x   + (size_t)bg * (Tt * Nn);
    float*       orow = out + (size_t)bg * (Tt * Nn);

    // prologue: publish h0 + x[0]; zero the pads of BOTH buffers once
    if (lane < 32) {
        xbuf[0][j] = act ? xrow[j] : 0.0f;
        hbuf[0][j] = act ? hv : 0.0f;
        xbuf[1][j] = 0.0f;
        hbuf[1][j] = 0.0f;
    }
    __builtin_amdgcn_wave_barrier();

    // x prefetch pipeline, distance ~2-3 iterations (covers HBM latency)
    float xn1 = pub ? xrow[1 * Nn + j] : 0.0f;   // x[t=1]
    float xn2 = pub ? xrow[2 * Nn + j] : 0.0f;   // x[t=2]

    // zx = bias + W_ih * x[0]  (x-contribution for step 0, log2e-scaled)
    float zx0, zx1, zx2, zx3;
    {
        const float4* xq = (const float4*)(&xbuf[0][k0]);
        const float4 v0 = xq[0], v1 = xq[1], v2 = xq[2], v3 = xq[3];
        const float4 xv[4] = {v0, v1, v2, v3};
        zx0 = bz0; zx1 = bz1; zx2 = bz2; zx3 = bz3;
#pragma unroll
        for (int q = 0; q < 4; ++q) {
            const float4 v = xv[q];
            zx0 = fmaf(wih[0][4*q+0], v.x, zx0); zx0 = fmaf(wih[0][4*q+1], v.y, zx0);
            zx0 = fmaf(wih[0][4*q+2], v.z, zx0); zx0 = fmaf(wih[0][4*q+3], v.w, zx0);
            zx1 = fmaf(wih[1][4*q+0], v.x, zx1); zx1 = fmaf(wih[1][4*q+1], v.y, zx1);
            zx1 = fmaf(wih[1][4*q+2], v.z, zx1); zx1 = fmaf(wih[1][4*q+3], v.w, zx1);
            zx2 = fmaf(wih[2][4*q+0], v.x, zx2); zx2 = fmaf(wih[2][4*q+1], v.y, zx2);
            zx2 = fmaf(wih[2][4*q+2], v.z, zx2); zx2 = fmaf(wih[2][4*q+3], v.w, zx2);
            zx3 = fmaf(wih[3][4*q+0], v.x, zx3); zx3 = fmaf(wih[3][4*q+1], v.y, zx3);
            zx3 = fmaf(wih[3][4*q+2], v.z, zx3); zx3 = fmaf(wih[3][4*q+3], v.w, zx3);
        }
    }

#pragma unroll 1
    for (int t = 0; t < Tt; ++t) {
        const int cur = t & 1;
        const int nxt = cur ^ 1;

        // 1. publish x[t+1] (register loaded 2 iterations ago)
        if (pub) xbuf[nxt][j] = xn1;
        __builtin_amdgcn_wave_barrier();

        // 2. issue global prefetch of x[t+3] (32-bit offsets; t3*Nn is SALU)
        int t3 = t + 3; t3 = (t3 < Tt) ? t3 : (Tt - 1);
        const float xnew = pub ? xrow[t3 * Nn + j] : 0.0f;

        // 3. h[t] chunk from LDS (wave-broadcast per half, conflict-free)
        const float4* hq = (const float4*)(&hbuf[cur][k0]);
        const float4 h0q = hq[0], h1q = hq[1], h2q = hq[2], h3q = hq[3];

        // 4. z = zx + W_hh*h ; fused out[t-1] partial = W_out*h   (80 FMA)
        float z0 = zx0, z1 = zx1, z2 = zx2, z3 = zx3;
        float oacc = bo;
        {
            const float4 hv4[4] = {h0q, h1q, h2q, h3q};
#pragma unroll
            for (int q = 0; q < 4; ++q) {
                const float4 v = hv4[q];
                z0 = fmaf(whh[0][4*q+0], v.x, z0); z0 = fmaf(whh[0][4*q+1], v.y, z0);
                z0 = fmaf(whh[0][4*q+2], v.z, z0); z0 = fmaf(whh[0][4*q+3], v.w, z0);
                z1 = fmaf(whh[1][4*q+0], v.x, z1); z1 = fmaf(whh[1][4*q+1], v.y, z1);
                z1 = fmaf(whh[1][4*q+2], v.z, z1); z1 = fmaf(whh[1][4*q+3], v.w, z1);
                z2 = fmaf(whh[2][4*q+0], v.x, z2); z2 = fmaf(whh[2][4*q+1], v.y, z2);
                z2 = fmaf(whh[2][4*q+2], v.z, z2); z2 = fmaf(whh[2][4*q+3], v.w, z2);
                z3 = fmaf(whh[3][4*q+0], v.x, z3); z3 = fmaf(whh[3][4*q+1], v.y, z3);
                z3 = fmaf(whh[3][4*q+2], v.z, z3); z3 = fmaf(whh[3][4*q+3], v.w, z3);
                oacc = fmaf(wout[4*q+0], v.x, oacc); oacc = fmaf(wout[4*q+1], v.y, oacc);
                oacc = fmaf(wout[4*q+2], v.z, oacc); oacc = fmaf(wout[4*q+3], v.w, oacc);
            }
        }

        // 5. combine the two k-halves
        z0 += __shfl_xor(z0, 32);
        z1 += __shfl_xor(z1, 32);
        z2 += __shfl_xor(z2, 32);
        z3 += __shfl_xor(z3, 32);
        oacc += __shfl_xor(oacc, 32);

        // 6. store out[t-1] (projection of h published last step)
        if (t > 0 && pub) orow[(t - 1) * Nn + j] = oacc;

        // 7. gates (z pre-scaled by log2e -> native exp2) + cell/state update
        const float ig = rcpf(1.0f + exp2f_fast(-z0));
        const float fg = rcpf(1.0f + exp2f_fast(-z1));
        const float gg = 1.0f - 2.0f * rcpf(1.0f + exp2f_fast(2.0f * z2));  // tanh
        const float og = rcpf(1.0f + exp2f_fast(-z3));
        c = fmaf(fg, c, ig * gg);
        const float tc = 1.0f - 2.0f * rcpf(1.0f + exp2f_fast((2.0f * LOG2E) * c));
        hv = og * tc;

        // 8. next step's x-contribution (independent of gates -> fills the
        //    serial tail; depends on xbuf[nxt] published at top of this iter)
        {
            const float4* xq = (const float4*)(&xbuf[nxt][k0]);
            const float4 v0 = xq[0], v1 = xq[1], v2 = xq[2], v3 = xq[3];
            const float4 xv[4] = {v0, v1, v2, v3};
            zx0 = bz0; zx1 = bz1; zx2 = bz2; zx3 = bz3;
#pragma unroll
            for (int q = 0; q < 4; ++q) {
                const float4 v = xv[q];
                zx0 = fmaf(wih[0][4*q+0], v.x, zx0); zx0 = fmaf(wih[0][4*q+1], v.y, zx0);
                zx0 = fmaf(wih[0][4*q+2], v.z, zx0); zx0 = fmaf(wih[0][4*q+3], v.w, zx0);
                zx1 = fmaf(wih[1][4*q+0], v.x, zx1); zx1 = fmaf(wih[1][4*q+1], v.y, zx1);
                zx1 = fmaf(wih[1][4*q+2], v.z, zx1); zx1 = fmaf(wih[1][4*q+3], v.w, zx1);
                zx2 = fmaf(wih[2][4*q+0], v.x, zx2); zx2 = fmaf(wih[2][4*q+1], v.y, zx2);
                zx2 = fmaf(wih[2][4*q+2], v.z, zx2); zx2 = fmaf(wih[2][4*q+3], v.w, zx2);
                zx3 = fmaf(wih[3][4*q+0], v.x, zx3); zx3 = fmaf(wih[3][4*q+1], v.y, zx3);
                zx3 = fmaf(wih[3][4*q+2], v.z, zx3); zx3 = fmaf(wih[3][4*q+3], v.w, zx3);
            }
        }

        // 9. publish h[t]
        if (pub) hbuf[nxt][j] = hv;
        __builtin_amdgcn_wave_barrier();
        xn1 = xn2;
        xn2 = xnew;
    }

    // epilogue: out[T-1] projection + final states (h is in hbuf[0]:
    // last publish wrote hbuf[(1023&1)^1] = hbuf[0])
    {
        const float4* hq = (const float4*)(&hbuf[0][k0]);
        const float4 h0q = hq[0], h1q = hq[1], h2q = hq[2], h3q = hq[3];
        const float4 hv4[4] = {h0q, h1q, h2q, h3q};
        float oacc = bo;
#pragma unroll
        for (int q = 0; q < 4; ++q) {
            const float4 v = hv4[q];
            oacc = fmaf(wout[4*q+0], v.x, oacc); oacc = fmaf(wout[4*q+1], v.y, oacc);
            oacc = fmaf(wout[4*q+2], v.z, oacc); oacc = fmaf(wout[4*q+3], v.w, oacc);
        }
        oacc += __shfl_xor(oacc, 32);
        if (pub) {
            orow[(Tt - 1) * Nn + j] = oacc;
            hn[bg * Nn + j] = hv;
            cn[bg * Nn + j] = c;
        }
    }
}

extern "C" void kernel_launch(void* const* d_in, const int* in_sizes, int n_in,
                              void* d_out, int out_size, void* d_ws, size_t ws_size,
                              hipStream_t stream) {
    const float* x     = (const float*)d_in[0];
    const float* h0    = (const float*)d_in[1];
    const float* c0    = (const float*)d_in[2];
    const float* W_ih  = (const float*)d_in[3];
    const float* W_hh  = (const float*)d_in[4];
    const float* b_ih  = (const float*)d_in[5];
    const float* b_hh  = (const float*)d_in[6];
    const float* W_out = (const float*)d_in[7];
    const float* b_out = (const float*)d_in[8];

    float* out = (float*)d_out;                          // [B,T,N]
    float* hn  = out + (size_t)Bb * Tt * Nn;             // [1,B,N]
    float* cn  = hn + (size_t)Bb * Nn;                   // [1,B,N]

    lstm_fused_kernel<<<dim3(Bb), dim3(64), 0, stream>>>(
        x, h0, c0, W_ih, W_hh, b_ih, b_hh, W_out, b_out, out, hn, cn);
}

// Round 6
// 985.874 us; speedup vs baseline: 1.3014x; 1.3014x over previous
//
#include <hip/hip_runtime.h>
#include <cstdint>

// Problem constants (fixed by setup_inputs in the reference)
constexpr int Bb = 2048;
constexpr int Tt = 1024;
constexpr int Nn = 27;
constexpr int KH = 16;   // k-half per lane (2 halves cover padded k=0..31)

__device__ __forceinline__ float rcpf(float a) { return __builtin_amdgcn_rcpf(a); }
__device__ __forceinline__ float exp2f_fast(float a) { return __builtin_amdgcn_exp2f(a); }

#define LOG2E 1.4426950408889634f

// 16 MACs into the 4 gate accumulators from one float4 of x/h
#define MAC16(A0, A1, A2, A3, W, q, v)                                        \
    A0 = fmaf(W[0][4*q+0], v.x, A0); A0 = fmaf(W[0][4*q+1], v.y, A0);         \
    A0 = fmaf(W[0][4*q+2], v.z, A0); A0 = fmaf(W[0][4*q+3], v.w, A0);         \
    A1 = fmaf(W[1][4*q+0], v.x, A1); A1 = fmaf(W[1][4*q+1], v.y, A1);         \
    A1 = fmaf(W[1][4*q+2], v.z, A1); A1 = fmaf(W[1][4*q+3], v.w, A1);         \
    A2 = fmaf(W[2][4*q+0], v.x, A2); A2 = fmaf(W[2][4*q+1], v.y, A2);         \
    A2 = fmaf(W[2][4*q+2], v.z, A2); A2 = fmaf(W[2][4*q+3], v.w, A2);         \
    A3 = fmaf(W[3][4*q+0], v.x, A3); A3 = fmaf(W[3][4*q+1], v.y, A3);         \
    A3 = fmaf(W[3][4*q+2], v.z, A3); A3 = fmaf(W[3][4*q+3], v.w, A3);

// Fused LSTM + output projection, fp32 (no fp32 MFMA on CDNA4 -> pure VALU).
//
// v5 (resubmit; round-5 bench never acquired a GPU): force arch-VGPR
// residency of the weight file.
// Post-mortem v2-v4: excess VALU/step scales with per-lane weight count
// (490 inst @ 292 wt, 196 inst @ 144 wt) => weights live in AGPRs and every
// use pays a v_accvgpr move. VGPR_Count=96 with ~200 peak pressure and a
// 256-reg budget means the allocator CHOSE a small arch split:
// __launch_bounds__(64,2) sets only a MINIMUM waves/EU, so RA targets higher
// occupancy and parks long-lived arrays in AGPRs. Fix: amdgpu_waves_per_eu(2,2)
// pins the target (budget exactly 256 unified regs/wave).
// Also: biases folded into weights via a constant-1 h-lane (k=27 slot of hbuf
// is 1.0 forever; bias row appended to whh/wout) -- saves 5 regs + 5 ops; all
// act?:-selects on global loads dropped (clamped addr + pub-gated publishes).
//
// Layout: 2048 single-wave blocks, one batch row per wave (2 waves/SIMD).
// lane = half*32 + j: j = hidden unit (j<27 active), half = 16-wide k-chunk.
// Weights per lane: 4x16 (W_ih) + 4x16 (W_hh) + 16 (W_out) = 144 VGPRs.
// Partial z per half, combined with __shfl_xor(.,32).
// zx (x-contribution for step t+1) is computed in step t's serial gate tail.
// W_ih/W_hh/biases pre-scaled by log2(e) so gates use native v_exp_f32 (exp2).
__global__ __launch_bounds__(64)
__attribute__((amdgpu_waves_per_eu(2, 2)))
void lstm_fused_kernel(
    const float* __restrict__ x,      // [B,T,N]
    const float* __restrict__ h0,     // [B,N]
    const float* __restrict__ c0,     // [B,N]
    const float* __restrict__ W_ih,   // [4N,N] gate order i,f,g,o
    const float* __restrict__ W_hh,   // [4N,N]
    const float* __restrict__ b_ih,   // [4N]
    const float* __restrict__ b_hh,   // [4N]
    const float* __restrict__ W_out,  // [N,N]
    const float* __restrict__ b_out,  // [N]
    float* __restrict__ out,          // [B,T,N]
    float* __restrict__ hn,           // [B,N]
    float* __restrict__ cn)           // [B,N]
{
    const int lane = threadIdx.x;         // 0..63
    const int j    = lane & 31;           // hidden unit
    const int half = lane >> 5;           // k-chunk index
    const int k0   = half * KH;           // first k of this lane's chunk
    const bool act = (j < Nn);
    const bool pub = (lane < Nn);         // half-0 active lanes: publish + store
    const int jj   = act ? j : (Nn - 1);  // clamped for safe loads
    const int bg   = blockIdx.x;          // batch row

    // one row per block; 32-wide. [27..31] pad: xbuf=0, hbuf[27]=1 (bias lane),
    // hbuf[28..31]=0. Publishes touch only j<27, so pads persist. dbl-buffered.
    __shared__ __align__(16) float xbuf[2][32];
    __shared__ __align__(16) float hbuf[2][32];

    // ---- weight chunks into registers ----
    // wih/whh pre-scaled by log2e (consumers are exp2-based gates).
    // k==27 column of whh carries the (log2e-scaled) gate bias; of wout, b_out.
    float wih[4][KH], whh[4][KH], wout[KH];
#pragma unroll
    for (int g = 0; g < 4; ++g) {
#pragma unroll
        for (int kk = 0; kk < KH; ++kk) {
            const int k = k0 + kk;
            wih[g][kk] = (k < Nn) ? W_ih[(g * Nn + jj) * Nn + k] * LOG2E : 0.0f;
            float w = 0.0f;
            if (k < Nn)       w = W_hh[(g * Nn + jj) * Nn + k] * LOG2E;
            else if (k == Nn) w = (b_ih[g * Nn + jj] + b_hh[g * Nn + jj]) * LOG2E;
            whh[g][kk] = w;
        }
    }
#pragma unroll
    for (int kk = 0; kk < KH; ++kk) {
        const int k = k0 + kk;
        wout[kk] = (k < Nn) ? W_out[jj * Nn + k] : ((k == Nn) ? b_out[jj] : 0.0f);
    }

    float c  = c0[bg * Nn + jj];   // cell state (duplicated across halves)
    float hv = h0[bg * Nn + jj];   // hidden state (duplicated)

    const float* xrow = x   + (size_t)bg * (Tt * Nn);
    float*       orow = out + (size_t)bg * (Tt * Nn);

    // prologue: publish h0 + x[0]; set pads (bias lane = 1.0) on BOTH buffers
    if (lane < 32) {
        xbuf[0][j] = act ? xrow[j] : 0.0f;
        xbuf[1][j] = 0.0f;
        hbuf[0][j] = act ? hv : ((j == Nn) ? 1.0f : 0.0f);
        hbuf[1][j] = (j == Nn) ? 1.0f : 0.0f;
    }
    __builtin_amdgcn_wave_barrier();

    // x prefetch pipeline, distance 2-3 iterations (covers HBM latency)
    float xn1 = xrow[1 * Nn + jj];   // x[t=1]
    float xn2 = xrow[2 * Nn + jj];   // x[t=2]

    // zx = W_ih * x[0]  (x-contribution for step 0; bias enters via h path)
    float zx0 = 0.0f, zx1 = 0.0f, zx2 = 0.0f, zx3 = 0.0f;
    {
        const float4* xq = (const float4*)(&xbuf[0][k0]);
        const float4 v0 = xq[0], v1 = xq[1], v2 = xq[2], v3 = xq[3];
        MAC16(zx0, zx1, zx2, zx3, wih, 0, v0)
        MAC16(zx0, zx1, zx2, zx3, wih, 1, v1)
        MAC16(zx0, zx1, zx2, zx3, wih, 2, v2)
        MAC16(zx0, zx1, zx2, zx3, wih, 3, v3)
    }

#pragma unroll 1
    for (int t = 0; t < Tt; ++t) {
        const int cur = t & 1;
        const int nxt = cur ^ 1;

        // 1. publish x[t+1] (register loaded 2 iterations ago)
        if (pub) xbuf[nxt][j] = xn1;
        __builtin_amdgcn_wave_barrier();

        // 2. issue global prefetch of x[t+3]
        int t3 = t + 3; t3 = (t3 < Tt) ? t3 : (Tt - 1);
        const float xnew = xrow[t3 * Nn + jj];

        // 3. h[t] chunk from LDS (wave-broadcast per half, conflict-free);
        //    k=27 slot is the constant-1 bias lane.
        const float4* hq = (const float4*)(&hbuf[cur][k0]);
        const float4 h0q = hq[0], h1q = hq[1], h2q = hq[2], h3q = hq[3];

        // 4. z = zx + W_hh*h(+bias) ; out[t-1] partial = W_out*h(+b_out)
        float z0 = zx0, z1 = zx1, z2 = zx2, z3 = zx3;
        float oacc = 0.0f;
        MAC16(z0, z1, z2, z3, whh, 0, h0q)
        MAC16(z0, z1, z2, z3, whh, 1, h1q)
        MAC16(z0, z1, z2, z3, whh, 2, h2q)
        MAC16(z0, z1, z2, z3, whh, 3, h3q)
        oacc = fmaf(wout[ 0], h0q.x, oacc); oacc = fmaf(wout[ 1], h0q.y, oacc);
        oacc = fmaf(wout[ 2], h0q.z, oacc); oacc = fmaf(wout[ 3], h0q.w, oacc);
        oacc = fmaf(wout[ 4], h1q.x, oacc); oacc = fmaf(wout[ 5], h1q.y, oacc);
        oacc = fmaf(wout[ 6], h1q.z, oacc); oacc = fmaf(wout[ 7], h1q.w, oacc);
        oacc = fmaf(wout[ 8], h2q.x, oacc); oacc = fmaf(wout[ 9], h2q.y, oacc);
        oacc = fmaf(wout[10], h2q.z, oacc); oacc = fmaf(wout[11], h2q.w, oacc);
        oacc = fmaf(wout[12], h3q.x, oacc); oacc = fmaf(wout[13], h3q.y, oacc);
        oacc = fmaf(wout[14], h3q.z, oacc); oacc = fmaf(wout[15], h3q.w, oacc);

        // 5. combine the two k-halves
        z0 += __shfl_xor(z0, 32);
        z1 += __shfl_xor(z1, 32);
        z2 += __shfl_xor(z2, 32);
        z3 += __shfl_xor(z3, 32);
        oacc += __shfl_xor(oacc, 32);

        // 6. store out[t-1] (projection of h published last step)
        if (t > 0 && pub) orow[(t - 1) * Nn + j] = oacc;

        // 7. gates (z pre-scaled by log2e -> native exp2) + cell/state update
        const float ig = rcpf(1.0f + exp2f_fast(-z0));
        const float fg = rcpf(1.0f + exp2f_fast(-z1));
        const float gg = 1.0f - 2.0f * rcpf(1.0f + exp2f_fast(2.0f * z2));  // tanh
        const float og = rcpf(1.0f + exp2f_fast(-z3));
        c = fmaf(fg, c, ig * gg);
        const float tc = 1.0f - 2.0f * rcpf(1.0f + exp2f_fast((2.0f * LOG2E) * c));
        hv = og * tc;

        // 8. next step's x-contribution (independent of gates -> fills the
        //    serial tail; depends on xbuf[nxt] published at top of this iter)
        {
            const float4* xq = (const float4*)(&xbuf[nxt][k0]);
            const float4 v0 = xq[0], v1 = xq[1], v2 = xq[2], v3 = xq[3];
            zx0 = 0.0f; zx1 = 0.0f; zx2 = 0.0f; zx3 = 0.0f;
            MAC16(zx0, zx1, zx2, zx3, wih, 0, v0)
            MAC16(zx0, zx1, zx2, zx3, wih, 1, v1)
            MAC16(zx0, zx1, zx2, zx3, wih, 2, v2)
            MAC16(zx0, zx1, zx2, zx3, wih, 3, v3)
        }

        // 9. publish h[t]
        if (pub) hbuf[nxt][j] = hv;
        __builtin_amdgcn_wave_barrier();
        xn1 = xn2;
        xn2 = xnew;
    }

    // epilogue: out[T-1] projection + final states (last publish -> hbuf[0])
    {
        const float4* hq = (const float4*)(&hbuf[0][k0]);
        const float4 h0q = hq[0], h1q = hq[1], h2q = hq[2], h3q = hq[3];
        float oacc = 0.0f;
        oacc = fmaf(wout[ 0], h0q.x, oacc); oacc = fmaf(wout[ 1], h0q.y, oacc);
        oacc = fmaf(wout[ 2], h0q.z, oacc); oacc = fmaf(wout[ 3], h0q.w, oacc);
        oacc = fmaf(wout[ 4], h1q.x, oacc); oacc = fmaf(wout[ 5], h1q.y, oacc);
        oacc = fmaf(wout[ 6], h1q.z, oacc); oacc = fmaf(wout[ 7], h1q.w, oacc);
        oacc = fmaf(wout[ 8], h2q.x, oacc); oacc = fmaf(wout[ 9], h2q.y, oacc);
        oacc = fmaf(wout[10], h2q.z, oacc); oacc = fmaf(wout[11], h2q.w, oacc);
        oacc = fmaf(wout[12], h3q.x, oacc); oacc = fmaf(wout[13], h3q.y, oacc);
        oacc = fmaf(wout[14], h3q.z, oacc); oacc = fmaf(wout[15], h3q.w, oacc);
        oacc += __shfl_xor(oacc, 32);
        if (pub) {
            orow[(Tt - 1) * Nn + j] = oacc;
            hn[bg * Nn + j] = hv;
            cn[bg * Nn + j] = c;
        }
    }
}

extern "C" void kernel_launch(void* const* d_in, const int* in_sizes, int n_in,
                              void* d_out, int out_size, void* d_ws, size_t ws_size,
                              hipStream_t stream) {
    const float* x     = (const float*)d_in[0];
    const float* h0    = (const float*)d_in[1];
    const float* c0    = (const float*)d_in[2];
    const float* W_ih  = (const float*)d_in[3];
    const float* W_hh  = (const float*)d_in[4];
    const float* b_ih  = (const float*)d_in[5];
    const float* b_hh  = (const float*)d_in[6];
    const float* W_out = (const float*)d_in[7];
    const float* b_out = (const float*)d_in[8];

    float* out = (float*)d_out;                          // [B,T,N]
    float* hn  = out + (size_t)Bb * Tt * Nn;             // [1,B,N]
    float* cn  = hn + (size_t)Bb * Nn;                   // [1,B,N]

    lstm_fused_kernel<<<dim3(Bb), dim3(64), 0, stream>>>(
        x, h0, c0, W_ih, W_hh, b_ih, b_hh, W_out, b_out, out, hn, cn);
}